// Round 3
// baseline (139.932 us; speedup 1.0000x reference)
//
#include <hip/hip_runtime.h>

// YOLO layer decode: input (B=16, A*(C+5)=255, H=76, W=76) fp32, anchors (3,2) fp32.
// Output boxes (B, A, H, W, 7): [xs, ys, ws, hs, conf, cls_prob, cls_id].
//
// R3: latency-bound fix — preload all 85 strided channel values into registers
// with a fully-unrolled load phase (fills the vmcnt queue, ~85 independent
// global_load_dword in flight) before any dependent compute. The R2 online
// softmax serialized loads behind the s/m dependency chain (139 us, 0.73 TB/s).

#define B_  16
#define A_  3
#define C_  80
#define H_  76
#define W_  76
#define PLANE (H_ * W_)   // 5776

__device__ __forceinline__ float fast_exp(float x) {
    return __builtin_amdgcn_exp2f(x * 1.44269504088896340736f);  // v_exp_f32 = 2^x
}

__device__ __forceinline__ float fast_rcp(float x) {
    return __builtin_amdgcn_rcpf(x);
}

__device__ __forceinline__ float sigmoidf(float x) {
    return fast_rcp(1.0f + fast_exp(-x));
}

__global__ __launch_bounds__(256) void yolo_kernel(const float* __restrict__ in,
                                                   const float* __restrict__ anchors,
                                                   float* __restrict__ out) {
    const int pos = blockIdx.x * 256 + threadIdx.x;   // y*W + x within one (b,a) plane
    if (pos >= PLANE) return;
    const int a = blockIdx.y;   // anchor index
    const int b = blockIdx.z;   // batch index

    const int x = pos % W_;
    const int y = pos / W_;

    const float* base = in + (size_t)(b * (A_ * (C_ + 5)) + a * (C_ + 5)) * PLANE + pos;

    // ---- Phase 1: issue ALL loads (independent addresses, no dependent use) ----
    float t[5];
    #pragma unroll
    for (int c = 0; c < 5; ++c) t[c] = base[c * PLANE];

    float l[C_];
    #pragma unroll
    for (int c = 0; c < C_; ++c) l[c] = base[(size_t)(5 + c) * PLANE];

    const float aw = anchors[2 * a + 0];   // wave-uniform scalar loads
    const float ah = anchors[2 * a + 1];

    // ---- Phase 2: compute from registers ----
    const float xs   = (sigmoidf(t[0]) + (float)x) * (1.0f / (float)W_);
    const float ys   = (sigmoidf(t[1]) + (float)y) * (1.0f / (float)H_);
    const float ws   = fast_exp(t[2]) * aw * (1.0f / (float)W_);
    const float hs   = fast_exp(t[3]) * ah * (1.0f / (float)H_);
    const float conf = sigmoidf(t[4]);

    // max + first-occurrence argmax (strict >, matches jnp.argmax)
    float m = l[0];
    int   id = 0;
    #pragma unroll
    for (int c = 1; c < C_; ++c) {
        if (l[c] > m) { m = l[c]; id = c; }
    }
    // softmax max-prob = exp(m - m) / sum = 1 / sum
    float s = 0.0f;
    #pragma unroll
    for (int c = 0; c < C_; ++c) s += fast_exp(l[c] - m);

    const float cls_prob = fast_rcp(s);
    const float cls_id   = (float)id;

    const size_t o = (size_t)((b * A_ + a) * PLANE + pos) * 7;
    out[o + 0] = xs;
    out[o + 1] = ys;
    out[o + 2] = ws;
    out[o + 3] = hs;
    out[o + 4] = conf;
    out[o + 5] = cls_prob;
    out[o + 6] = cls_id;
}

extern "C" void kernel_launch(void* const* d_in, const int* in_sizes, int n_in,
                              void* d_out, int out_size, void* d_ws, size_t ws_size,
                              hipStream_t stream) {
    const float* in      = (const float*)d_in[0];
    const float* anchors = (const float*)d_in[1];
    float* out           = (float*)d_out;

    dim3 grid((PLANE + 255) / 256, A_, B_);   // (23, 3, 16)
    dim3 block(256, 1, 1);
    yolo_kernel<<<grid, block, 0, stream>>>(in, anchors, out);
}

// Round 4
// 136.595 us; speedup vs baseline: 1.0244x; 1.0244x over previous
//
#include <hip/hip_runtime.h>

// YOLO layer decode: input (B=16, A*(C+5)=255, H=76, W=76) fp32, anchors (3,2) fp32.
// Output boxes (B, A, H, W, 7): [xs, ys, ws, hs, conf, cls_prob, cls_id].
//
// R4: class-split parallelization. R2/R3 were identical at 139 us with one
// thread per position (4332 waves = 4.2/SIMD, 85 loads + ~90 exps per thread).
// Now: block = 4 waves over 64 positions; wave w handles classes [20w,20w+20)
// (coalesced 256B loads), partials (m, s, id) merged via LDS with rescale
// S = sum s_w * exp(m_w - M). 4x wave count -> 8 resident waves/SIMD, and
// output staged in LDS then written as 2 contiguous coalesced stores/block.

#define B_  16
#define A_  3
#define C_  80
#define H_  76
#define W_  76
#define PLANE (H_ * W_)   // 5776
#define CPW  20           // classes per wave (4 waves * 20 = 80)

__device__ __forceinline__ float fast_exp(float x) {
    return __builtin_amdgcn_exp2f(x * 1.44269504088896340736f);  // v_exp_f32 = 2^x
}

__device__ __forceinline__ float fast_rcp(float x) {
    return __builtin_amdgcn_rcpf(x);
}

__device__ __forceinline__ float sigmoidf(float x) {
    return fast_rcp(1.0f + fast_exp(-x));
}

__global__ __launch_bounds__(256) void yolo_kernel(const float* __restrict__ in,
                                                   const float* __restrict__ anchors,
                                                   float* __restrict__ out) {
    const int tid  = threadIdx.x;
    const int lane = tid & 63;
    const int wid  = tid >> 6;          // 0..3: which class group
    const int a = blockIdx.y;
    const int b = blockIdx.z;
    const int pos_base = blockIdx.x * 64;
    const int pos  = pos_base + lane;
    const int posc = (pos < PLANE) ? pos : (PLANE - 1);   // clamp for safe loads

    const float* base = in + (size_t)((b * A_ + a) * (C_ + 5)) * PLANE + posc;

    // ---- class loads: 20 independent coalesced 256B loads per wave ----
    const float* cb = base + (size_t)(5 + wid * CPW) * PLANE;
    float l[CPW];
    #pragma unroll
    for (int j = 0; j < CPW; ++j) l[j] = cb[(size_t)j * PLANE];

    // box channels: wave 0 only (wave-uniform branch)
    float t0 = 0.f, t1 = 0.f, t2 = 0.f, t3 = 0.f, t4 = 0.f;
    if (wid == 0) {
        t0 = base[0 * PLANE];
        t1 = base[1 * PLANE];
        t2 = base[2 * PLANE];
        t3 = base[3 * PLANE];
        t4 = base[4 * PLANE];
    }

    // ---- per-wave partial max / first-occurrence argmax / expsum ----
    float m = l[0];
    int   id = 0;
    #pragma unroll
    for (int j = 1; j < CPW; ++j) {
        if (l[j] > m) { m = l[j]; id = j; }
    }
    float s = 0.0f;
    #pragma unroll
    for (int j = 0; j < CPW; ++j) s += fast_exp(l[j] - m);

    __shared__ float sm[4][64];
    __shared__ float ss[4][64];
    __shared__ int   sid[4][64];
    __shared__ float res[64 * 7];

    sm[wid][lane]  = m;
    ss[wid][lane]  = s;
    sid[wid][lane] = id + wid * CPW;
    __syncthreads();

    if (wid == 0) {
        // combine in increasing wid order, strict > => global first-occurrence argmax
        float M  = sm[0][lane];
        int   ID = sid[0][lane];
        #pragma unroll
        for (int w = 1; w < 4; ++w) {
            const float mw = sm[w][lane];
            if (mw > M) { M = mw; ID = sid[w][lane]; }
        }
        float S = 0.0f;
        #pragma unroll
        for (int w = 0; w < 4; ++w) S += ss[w][lane] * fast_exp(sm[w][lane] - M);

        const int x = posc % W_;
        const int y = posc / W_;
        const float aw = anchors[2 * a + 0];
        const float ah = anchors[2 * a + 1];

        res[lane * 7 + 0] = (sigmoidf(t0) + (float)x) * (1.0f / (float)W_);
        res[lane * 7 + 1] = (sigmoidf(t1) + (float)y) * (1.0f / (float)H_);
        res[lane * 7 + 2] = fast_exp(t2) * aw * (1.0f / (float)W_);
        res[lane * 7 + 3] = fast_exp(t3) * ah * (1.0f / (float)H_);
        res[lane * 7 + 4] = sigmoidf(t4);
        res[lane * 7 + 5] = fast_rcp(S);
        res[lane * 7 + 6] = (float)ID;
    }
    __syncthreads();

    // ---- coalesced store: 448 contiguous floats per block ----
    const size_t obase = (size_t)((b * A_ + a) * PLANE + pos_base) * 7;
    #pragma unroll
    for (int k = 0; k < 2; ++k) {
        const int f = tid + k * 256;
        if (f < 64 * 7 && (pos_base + f / 7) < PLANE) {
            out[obase + f] = res[f];
        }
    }
}

extern "C" void kernel_launch(void* const* d_in, const int* in_sizes, int n_in,
                              void* d_out, int out_size, void* d_ws, size_t ws_size,
                              hipStream_t stream) {
    const float* in      = (const float*)d_in[0];
    const float* anchors = (const float*)d_in[1];
    float* out           = (float*)d_out;

    dim3 grid((PLANE + 63) / 64, A_, B_);   // (91, 3, 16) = 4368 blocks, 4 waves each
    dim3 block(256, 1, 1);
    yolo_kernel<<<grid, block, 0, stream>>>(in, anchors, out);
}